// Round 8
// baseline (2481.710 us; speedup 1.0000x reference)
//
#include <hip/hip_runtime.h>

// DualEmbedding v8 — ABLATION ROUND. Production kernels = v7 (champion, 267us)
// unchanged. Four probe kernels (x4 reps each, so they beat the ~313us harness
// fills into rocprof top-5) isolate the edge kernel's cost streams:
//   probe<0> FULL      — exact edge-kernel work, x4
//   probe<1> NOGATHER  — h_node gather loads removed (idx loads kept alive)
//   probe<2> NOX       — x_edge loads removed
//   probe<3> NOSTORE   — out stores removed (values kept alive via asm)
// Launch order: node -> probes (may write garbage to d_out) -> REAL edge
// kernel last, which rewrites every out row => output correct+deterministic.

typedef __attribute__((ext_vector_type(8))) short bf16x8;
typedef __attribute__((ext_vector_type(4))) float f32x4;

__device__ __forceinline__ short f2bf(float f) {          // RTNE f32->bf16
  unsigned u = __float_as_uint(f);
  u = (u + 0x7FFFu + ((u >> 16) & 1u)) >> 16;
  return (short)u;
}
__device__ __forceinline__ float bf2f(short s) {
  return __uint_as_float(((unsigned)(unsigned short)s) << 16);
}
__device__ __forceinline__ bf16x8 cvt8(const float* __restrict__ p) {
  const f32x4 a = *(const f32x4*)p;
  const f32x4 b = *(const f32x4*)(p + 4);
  bf16x8 r;
  r[0] = f2bf(a[0]); r[1] = f2bf(a[1]); r[2] = f2bf(a[2]); r[3] = f2bf(a[3]);
  r[4] = f2bf(b[0]); r[5] = f2bf(b[1]); r[6] = f2bf(b[2]); r[7] = f2bf(b[3]);
  return r;
}

// ---------------- node projection -> permuted bf16 table -------------------
__global__ __launch_bounds__(256) void node_mfma_kernel(
    const float* __restrict__ x_node,
    const float* __restrict__ W_node,
    const float* __restrict__ b_node,
    short* __restrict__ h_node,          // [N][128] bf16, (k,g)-chunked
    int n_nodes)
{
  const int lane = threadIdx.x & 63;
  const int c = lane & 15, g = lane >> 4;
  const int gw = blockIdx.x * 4 + (threadIdx.x >> 6);
  const int nw = gridDim.x * 4;
  const int ntiles = (n_nodes + 15) >> 4;

  bf16x8 aW[8][4];
#pragma unroll
  for (int t = 0; t < 8; ++t)
#pragma unroll
    for (int s = 0; s < 4; ++s)
      aW[t][s] = cvt8(W_node + (size_t)(16 * t + c) * 128 + 32 * s + 8 * g);

  for (int tile = gw; tile < ntiles; tile += nw) {
    const int n0 = tile << 4;
    const int n = (n0 + c < n_nodes) ? n0 + c : n_nodes - 1;
    const float* xr = x_node + (size_t)n * 128;
    bf16x8 bx[4];
#pragma unroll
    for (int s = 0; s < 4; ++s) bx[s] = cvt8(xr + 32 * s + 8 * g);

    f32x4 acc[8];
#pragma unroll
    for (int t = 0; t < 8; ++t)
      acc[t] = *(const f32x4*)(b_node + 16 * t + 4 * g);
#pragma unroll
    for (int t = 0; t < 8; ++t)
#pragma unroll
      for (int s = 0; s < 4; ++s)
        acc[t] = __builtin_amdgcn_mfma_f32_16x16x32_bf16(aW[t][s], bx[s], acc[t], 0, 0, 0);

    if (n0 + c < n_nodes) {
      short* o = h_node + (size_t)(n0 + c) * 128 + g * 8;
#pragma unroll
      for (int k = 0; k < 4; ++k) {
        bf16x8 v;
#pragma unroll
        for (int j = 0; j < 4; ++j) {
          v[j]     = f2bf(acc[2 * k][j]);
          v[4 + j] = f2bf(acc[2 * k + 1][j]);
        }
        *(bf16x8*)(o + 32 * k) = v;
      }
    }
  }
}

// ---------------- shared edge-kernel body (templated for ablation) ---------
// MODE: 0 = FULL (production when REPS=1), 1 = NOGATHER, 2 = NOX, 3 = NOSTORE
template <int MODE, int REPS>
__device__ __forceinline__ void edge_body(
    const float* __restrict__ x_edge,
    const int*   __restrict__ eidx,
    const float* __restrict__ W_edge,
    const float* __restrict__ b_edge,
    const short* __restrict__ h_node,
    const float* __restrict__ gamma,
    const float* __restrict__ beta,
    float* __restrict__ out,
    int n_edges)
{
  __shared__ short Wlds[8192];
  __shared__ float plds[384];

  const int tid = threadIdx.x;
  {
    const int r = tid >> 1, h = tid & 1;
    const float* wr = W_edge + (size_t)r * 64 + 32 * h;
#pragma unroll
    for (int q = 0; q < 4; ++q) {
      const bf16x8 v = cvt8(wr + 8 * q);
      const int slot = (4 * h + q) ^ (r & 7);
      *(bf16x8*)(&Wlds[r * 64 + slot * 8]) = v;
    }
    if (tid < 128) {
      plds[tid]       = b_edge[tid];
      plds[128 + tid] = gamma[tid];
      plds[256 + tid] = beta[tid];
    }
  }
  __syncthreads();

  const int lane = tid & 63;
  const int c = lane & 15, g = lane >> 4;
  const int gw = blockIdx.x * 4 + (tid >> 6);
  const int nw = gridDim.x * 4;
  const int ntiles = (n_edges + 15) >> 4;

  const int w0off = c * 64 + ((g) ^ (c & 7)) * 8;
  const int w1off = c * 64 + ((4 + g) ^ (c & 7)) * 8;

  if (gw >= ntiles) return;

  // opaque junk fragment (LDS-sourced; not constant-foldable) for skip modes
  const bf16x8 junk = *(const bf16x8*)(&Wlds[w0off]);

  auto LOADIDX = [&](int tile, int& src, int& dst) {
    const int e = (tile * 16 + c < n_edges) ? tile * 16 + c : n_edges - 1;
    src = eidx[e];
    dst = eidx[n_edges + e];
  };
  auto LOADX = [&](int tile, bf16x8& b0, bf16x8& b1) {
    const int e = (tile * 16 + c < n_edges) ? tile * 16 + c : n_edges - 1;
    if constexpr (MODE == 2) {
      asm volatile("" :: "v"(e));      // keep addr math, drop the loads
      b0 = junk; b1 = junk;
    } else {
      const float* xr = x_edge + (size_t)e * 64;
      b0 = cvt8(xr + 8 * g);
      b1 = cvt8(xr + 32 + 8 * g);
    }
  };
  auto GATHER = [&](int src, int dst, bf16x8* vs, bf16x8* vd) {
    if constexpr (MODE == 1) {
      asm volatile("" :: "v"(src), "v"(dst));  // keep idx loads live
#pragma unroll
      for (int k = 0; k < 4; ++k) { vs[k] = junk; vd[k] = junk; }
    } else {
      const short* hs = h_node + (size_t)src * 128 + g * 8;
      const short* hd = h_node + (size_t)dst * 128 + g * 8;
#pragma unroll
      for (int k = 0; k < 4; ++k) {
        vs[k] = *(const bf16x8*)(hs + 32 * k);
        vd[k] = *(const bf16x8*)(hd + 32 * k);
      }
    }
  };
  auto COMPUTE = [&](int tile, bf16x8 b0, bf16x8 b1, bf16x8* vs, bf16x8* vd) {
    f32x4 acc[8];
#pragma unroll
    for (int k = 0; k < 4; ++k)
#pragma unroll
      for (int j = 0; j < 4; ++j) {
        acc[2 * k][j]     = plds[16 * (2 * k) + 4 * g + j]
                          + 0.5f * (bf2f(vs[k][j]) + bf2f(vd[k][j]));
        acc[2 * k + 1][j] = plds[16 * (2 * k + 1) + 4 * g + j]
                          + 0.5f * (bf2f(vs[k][4 + j]) + bf2f(vd[k][4 + j]));
      }
#pragma unroll
    for (int t = 0; t < 8; ++t) {
      const bf16x8 a0 = *(const bf16x8*)(&Wlds[t * 1024 + w0off]);
      const bf16x8 a1 = *(const bf16x8*)(&Wlds[t * 1024 + w1off]);
      acc[t] = __builtin_amdgcn_mfma_f32_16x16x32_bf16(a0, b0, acc[t], 0, 0, 0);
      acc[t] = __builtin_amdgcn_mfma_f32_16x16x32_bf16(a1, b1, acc[t], 0, 0, 0);
    }
    float s1 = 0.f;
#pragma unroll
    for (int t = 0; t < 8; ++t)
      s1 += (acc[t][0] + acc[t][1]) + (acc[t][2] + acc[t][3]);
    s1 += __shfl_xor(s1, 16, 64);
    s1 += __shfl_xor(s1, 32, 64);
    const float mu = s1 * (1.f / 128.f);

    float s2 = 0.f;
#pragma unroll
    for (int t = 0; t < 8; ++t)
#pragma unroll
      for (int j = 0; j < 4; ++j) {
        const float d = acc[t][j] - mu;
        acc[t][j] = d;
        s2 = fmaf(d, d, s2);
      }
    s2 += __shfl_xor(s2, 16, 64);
    s2 += __shfl_xor(s2, 32, 64);
    const float rstd = rsqrtf(s2 * (1.f / 128.f) + 1e-5f);

    if (tile * 16 + c < n_edges) {
      float* o = out + (size_t)(tile * 16 + c) * 128 + 4 * g;
#pragma unroll
      for (int t = 0; t < 8; ++t) {
        f32x4 r;
#pragma unroll
        for (int j = 0; j < 4; ++j)
          r[j] = fmaf(acc[t][j] * rstd, plds[128 + 16 * t + 4 * g + j],
                      plds[256 + 16 * t + 4 * g + j]);
        if constexpr (MODE == 3)
          asm volatile("" :: "v"(r[0]), "v"(r[1]), "v"(r[2]), "v"(r[3]));
        else
          *(f32x4*)(o + 16 * t) = r;
      }
    }
  };

  for (int rp = 0; rp < REPS; ++rp) {
    bf16x8 bxA0, bxA1, bxB0, bxB1;
    bf16x8 vsA[4], vdA[4], vsB[4], vdB[4];
    int srcA, dstA, srcB, dstB;

    LOADIDX(gw, srcA, dstA);
    LOADX(gw, bxA0, bxA1);
    GATHER(srcA, dstA, vsA, vdA);
    LOADIDX(gw + nw, srcB, dstB);
    LOADX(gw + nw, bxB0, bxB1);

    int t = gw;
    for (;;) {
      GATHER(srcB, dstB, vsB, vdB);
      LOADIDX(t + 2 * nw, srcA, dstA);
      COMPUTE(t, bxA0, bxA1, vsA, vdA);
      LOADX(t + 2 * nw, bxA0, bxA1);
      t += nw;
      if (t >= ntiles) break;

      GATHER(srcA, dstA, vsA, vdA);
      LOADIDX(t + 2 * nw, srcB, dstB);
      COMPUTE(t, bxB0, bxB1, vsB, vdB);
      LOADX(t + 2 * nw, bxB0, bxB1);
      t += nw;
      if (t >= ntiles) break;
    }
  }
}

__global__ __launch_bounds__(256) void edge_mfma_kernel(
    const float* __restrict__ x_edge, const int* __restrict__ eidx,
    const float* __restrict__ W_edge, const float* __restrict__ b_edge,
    const short* __restrict__ h_node, const float* __restrict__ gamma,
    const float* __restrict__ beta, float* __restrict__ out, int n_edges)
{
  edge_body<0, 1>(x_edge, eidx, W_edge, b_edge, h_node, gamma, beta, out, n_edges);
}

template <int MODE>
__global__ __launch_bounds__(256) void probe_kernel(
    const float* __restrict__ x_edge, const int* __restrict__ eidx,
    const float* __restrict__ W_edge, const float* __restrict__ b_edge,
    const short* __restrict__ h_node, const float* __restrict__ gamma,
    const float* __restrict__ beta, float* __restrict__ out, int n_edges)
{
  edge_body<MODE, 4>(x_edge, eidx, W_edge, b_edge, h_node, gamma, beta, out, n_edges);
}

extern "C" void kernel_launch(void* const* d_in, const int* in_sizes, int n_in,
                              void* d_out, int out_size, void* d_ws, size_t ws_size,
                              hipStream_t stream) {
  const float* x_node = (const float*)d_in[0];
  const float* x_edge = (const float*)d_in[1];
  const int*   eidx   = (const int*)  d_in[2];
  const float* W_edge = (const float*)d_in[3];
  const float* b_edge = (const float*)d_in[4];
  const float* W_node = (const float*)d_in[5];
  const float* b_node = (const float*)d_in[6];
  const float* gamma  = (const float*)d_in[7];
  const float* beta   = (const float*)d_in[8];
  float* out = (float*)d_out;

  const int n_nodes = in_sizes[0] / 128;
  const int n_edges = in_sizes[2] / 2;

  short* h_node = (short*)d_ws;
  if (ws_size < (size_t)n_nodes * 128 * sizeof(short)) return;

  node_mfma_kernel<<<512, 256, 0, stream>>>(x_node, W_node, b_node, h_node, n_nodes);

  // ---- ablation probes (x4 each; may write garbage to d_out) ----
  probe_kernel<0><<<2048, 256, 0, stream>>>(x_edge, eidx, W_edge, b_edge,
                                            h_node, gamma, beta, out, n_edges);
  probe_kernel<1><<<2048, 256, 0, stream>>>(x_edge, eidx, W_edge, b_edge,
                                            h_node, gamma, beta, out, n_edges);
  probe_kernel<2><<<2048, 256, 0, stream>>>(x_edge, eidx, W_edge, b_edge,
                                            h_node, gamma, beta, out, n_edges);
  probe_kernel<3><<<2048, 256, 0, stream>>>(x_edge, eidx, W_edge, b_edge,
                                            h_node, gamma, beta, out, n_edges);

  // ---- REAL edge kernel LAST: rewrites every out row -> correct output ----
  edge_mfma_kernel<<<2048, 256, 0, stream>>>(x_edge, eidx, W_edge, b_edge,
                                             h_node, gamma, beta, out, n_edges);
}

// Round 9
// 246.738 us; speedup vs baseline: 10.0581x; 10.0581x over previous
//
#include <hip/hip_runtime.h>

// DualEmbedding v9 — v6 restructure WITHOUT the launch_bounds cap (v6's
// regression was the VGPR=48 cap forcing scratch spills, not the structure):
//  * node: W_node in swizzled LDS -> VGPR ~95, 4-5 waves/SIMD (was ~200 / 2).
//  * edge: single-buffered gather pipeline (consume-at-top, reissue same regs),
//    natural allocation targeting ~100 VGPR for 5 waves/SIMD.
//  * h_node (k,g)-chunk layout from v7 (contiguous 64B per gather instr).
//
// Kernel A (node): h_node_bf16[node]: chunk(g,k) at byte k*64+g*16 holds
//   dims {16*(2k)+4g+j, 16*(2k+1)+4g+j}, j=0..3 (bf16).
// Kernel B (edge): out = LN(x_edge @ W_edge.T + b_edge + 0.5*(h[src]+h[dst]))
//
// MFMA mapping (16x16x32 bf16): C tile t, lane(c=lane&15,g=lane>>4), reg j =
//   C[dim=16t+4g+j][row base+c]  -> each lane owns all 128 dims of ONE row.
// LDS W layout: row r, 8-bf16 slot sigma stored at sigma^(r&7) — measured 0
// bank conflicts (R4/R6).

typedef __attribute__((ext_vector_type(8))) short bf16x8;
typedef __attribute__((ext_vector_type(4))) float f32x4;

__device__ __forceinline__ short f2bf(float f) {          // RTNE f32->bf16
  unsigned u = __float_as_uint(f);
  u = (u + 0x7FFFu + ((u >> 16) & 1u)) >> 16;
  return (short)u;
}
__device__ __forceinline__ float bf2f(short s) {
  return __uint_as_float(((unsigned)(unsigned short)s) << 16);
}
__device__ __forceinline__ bf16x8 cvt8(const float* __restrict__ p) {
  const f32x4 a = *(const f32x4*)p;
  const f32x4 b = *(const f32x4*)(p + 4);
  bf16x8 r;
  r[0] = f2bf(a[0]); r[1] = f2bf(a[1]); r[2] = f2bf(a[2]); r[3] = f2bf(a[3]);
  r[4] = f2bf(b[0]); r[5] = f2bf(b[1]); r[6] = f2bf(b[2]); r[7] = f2bf(b[3]);
  return r;
}

// ---------------- node projection -> permuted bf16 table -------------------
__global__ __launch_bounds__(256) void node_mfma_kernel(
    const float* __restrict__ x_node,
    const float* __restrict__ W_node,
    const float* __restrict__ b_node,
    short* __restrict__ h_node,          // [N][128] bf16, (k,g)-chunked
    int n_nodes)
{
  __shared__ short Wlds[16384];         // 128 rows x 128 bf16 = 32 KB, swizzled
  __shared__ float blds[128];

  const int tid = threadIdx.x;
  {
    const int r = tid >> 1, h = tid & 1;      // row, which 64-col half
    const float* wr = W_node + (size_t)r * 128 + 64 * h;
#pragma unroll
    for (int q = 0; q < 8; ++q) {
      const bf16x8 v = cvt8(wr + 8 * q);
      const int slot = (8 * h + q) ^ (r & 7);
      *(bf16x8*)(&Wlds[r * 128 + slot * 8]) = v;
    }
    if (tid < 128) blds[tid] = b_node[tid];
  }
  __syncthreads();

  const int lane = tid & 63;
  const int c = lane & 15, g = lane >> 4;
  const int gw = blockIdx.x * 4 + (tid >> 6);
  const int nw = gridDim.x * 4;
  const int ntiles = (n_nodes + 15) >> 4;

  // per-lane swizzled LDS short-offsets for A fragments, s in 0..3
  int woff[4];
#pragma unroll
  for (int s = 0; s < 4; ++s) woff[s] = c * 128 + ((4 * s + g) ^ (c & 7)) * 8;

  for (int tile = gw; tile < ntiles; tile += nw) {
    const int n0 = tile << 4;
    const int n = (n0 + c < n_nodes) ? n0 + c : n_nodes - 1;
    const float* xr = x_node + (size_t)n * 128;
    bf16x8 bx[4];
#pragma unroll
    for (int s = 0; s < 4; ++s) bx[s] = cvt8(xr + 32 * s + 8 * g);

    f32x4 acc[8];
#pragma unroll
    for (int t = 0; t < 8; ++t)
      acc[t] = *(const f32x4*)(blds + 16 * t + 4 * g);
#pragma unroll
    for (int t = 0; t < 8; ++t)
#pragma unroll
      for (int s = 0; s < 4; ++s) {
        const bf16x8 a = *(const bf16x8*)(&Wlds[t * 2048 + woff[s]]);
        acc[t] = __builtin_amdgcn_mfma_f32_16x16x32_bf16(a, bx[s], acc[t], 0, 0, 0);
      }

    if (n0 + c < n_nodes) {
      // chunk (g,k) at elements k*32+g*8 -> store instr k covers one
      // contiguous 64B line per row across g=0..3
      short* o = h_node + (size_t)(n0 + c) * 128 + g * 8;
#pragma unroll
      for (int k = 0; k < 4; ++k) {
        bf16x8 v;
#pragma unroll
        for (int j = 0; j < 4; ++j) {
          v[j]     = f2bf(acc[2 * k][j]);
          v[4 + j] = f2bf(acc[2 * k + 1][j]);
        }
        *(bf16x8*)(o + 32 * k) = v;
      }
    }
  }
}

// ---------------- fused edge: GEMM + gather + LayerNorm --------------------
__global__ __launch_bounds__(256) void edge_mfma_kernel(
    const float* __restrict__ x_edge,
    const int*   __restrict__ eidx,      // [2, E] int32
    const float* __restrict__ W_edge,
    const float* __restrict__ b_edge,
    const short* __restrict__ h_node,    // permuted bf16, (k,g)-chunked
    const float* __restrict__ gamma,
    const float* __restrict__ beta,
    float* __restrict__ out,
    int n_edges)
{
  __shared__ short Wlds[8192];          // 128 rows x 64 bf16 = 16 KB, swizzled
  __shared__ float plds[384];           // bias | gamma | beta

  const int tid = threadIdx.x;
  {
    const int r = tid >> 1, h = tid & 1;
    const float* wr = W_edge + (size_t)r * 64 + 32 * h;
#pragma unroll
    for (int q = 0; q < 4; ++q) {
      const bf16x8 v = cvt8(wr + 8 * q);
      const int slot = (4 * h + q) ^ (r & 7);
      *(bf16x8*)(&Wlds[r * 64 + slot * 8]) = v;
    }
    if (tid < 128) {
      plds[tid]       = b_edge[tid];
      plds[128 + tid] = gamma[tid];
      plds[256 + tid] = beta[tid];
    }
  }
  __syncthreads();

  const int lane = tid & 63;
  const int c = lane & 15, g = lane >> 4;
  const int gw = blockIdx.x * 4 + (tid >> 6);
  const int nw = gridDim.x * 4;
  const int ntiles = (n_edges + 15) >> 4;

  const int w0off = c * 64 + ((g) ^ (c & 7)) * 8;
  const int w1off = c * 64 + ((4 + g) ^ (c & 7)) * 8;

  if (gw >= ntiles) return;

  auto LOADIDX = [&](int tile, int& src, int& dst) {
    const int e = (tile * 16 + c < n_edges) ? tile * 16 + c : n_edges - 1;
    src = eidx[e];
    dst = eidx[n_edges + e];
  };
  auto LOADX = [&](int tile, bf16x8& b0, bf16x8& b1) {
    const int e = (tile * 16 + c < n_edges) ? tile * 16 + c : n_edges - 1;
    const float* xr = x_edge + (size_t)e * 64;
    b0 = cvt8(xr + 8 * g);
    b1 = cvt8(xr + 32 + 8 * g);
  };
  auto GATHER = [&](int src, int dst, bf16x8* vs, bf16x8* vd) {
    // (k,g)-chunks: instr k reads one contiguous 64B line per edge-row
    const short* hs = h_node + (size_t)src * 128 + g * 8;
    const short* hd = h_node + (size_t)dst * 128 + g * 8;
#pragma unroll
    for (int k = 0; k < 4; ++k) {
      vs[k] = *(const bf16x8*)(hs + 32 * k);
      vd[k] = *(const bf16x8*)(hd + 32 * k);
    }
  };

  // ---- pipeline state (single-buffered gathers) -------------------------
  bf16x8 bx0, bx1, bxN0, bxN1;
  bf16x8 vs[4], vd[4];
  int srcN, dstN;

  // prologue: tile gw fully staged; idx for gw+nw ready
  {
    int src0, dst0;
    LOADIDX(gw, src0, dst0);
    LOADX(gw, bx0, bx1);
    GATHER(src0, dst0, vs, vd);
    LOADIDX(gw + nw, srcN, dstN);
  }

  for (int t = gw; t < ntiles; t += nw) {
    // 1) fold tile-t gathers into acc init (issued one iteration ago)
    f32x4 acc[8];
#pragma unroll
    for (int k = 0; k < 4; ++k)
#pragma unroll
      for (int j = 0; j < 4; ++j) {
        acc[2 * k][j]     = plds[16 * (2 * k) + 4 * g + j]
                          + 0.5f * (bf2f(vs[k][j]) + bf2f(vd[k][j]));
        acc[2 * k + 1][j] = plds[16 * (2 * k + 1) + 4 * g + j]
                          + 0.5f * (bf2f(vs[k][4 + j]) + bf2f(vd[k][4 + j]));
      }

    // 2) reuse freed vs/vd: issue gathers for tile t+nw
    GATHER(srcN, dstN, vs, vd);
    // 3) prefetch idx for t+2nw and x for t+nw
    LOADIDX(t + 2 * nw, srcN, dstN);
    LOADX(t + nw, bxN0, bxN1);

    // 4) GEMM for tile t (A from swizzled LDS)
#pragma unroll
    for (int tt = 0; tt < 8; ++tt) {
      const bf16x8 a0 = *(const bf16x8*)(&Wlds[tt * 1024 + w0off]);
      const bf16x8 a1 = *(const bf16x8*)(&Wlds[tt * 1024 + w1off]);
      acc[tt] = __builtin_amdgcn_mfma_f32_16x16x32_bf16(a0, bx0, acc[tt], 0, 0, 0);
      acc[tt] = __builtin_amdgcn_mfma_f32_16x16x32_bf16(a1, bx1, acc[tt], 0, 0, 0);
    }

    // 5) LayerNorm (dims of one edge split over lanes c, c+16, c+32, c+48)
    float s1 = 0.f;
#pragma unroll
    for (int tt = 0; tt < 8; ++tt)
      s1 += (acc[tt][0] + acc[tt][1]) + (acc[tt][2] + acc[tt][3]);
    s1 += __shfl_xor(s1, 16, 64);
    s1 += __shfl_xor(s1, 32, 64);
    const float mu = s1 * (1.f / 128.f);

    float s2 = 0.f;
#pragma unroll
    for (int tt = 0; tt < 8; ++tt)
#pragma unroll
      for (int j = 0; j < 4; ++j) {
        const float d = acc[tt][j] - mu;
        acc[tt][j] = d;
        s2 = fmaf(d, d, s2);
      }
    s2 += __shfl_xor(s2, 16, 64);
    s2 += __shfl_xor(s2, 32, 64);
    const float rstd = rsqrtf(s2 * (1.f / 128.f) + 1e-5f);

    // 6) store
    if (t * 16 + c < n_edges) {
      float* o = out + (size_t)(t * 16 + c) * 128 + 4 * g;
#pragma unroll
      for (int tt = 0; tt < 8; ++tt) {
        f32x4 r;
#pragma unroll
        for (int j = 0; j < 4; ++j)
          r[j] = fmaf(acc[tt][j] * rstd, plds[128 + 16 * tt + 4 * g + j],
                      plds[256 + 16 * tt + 4 * g + j]);
        *(f32x4*)(o + 16 * tt) = r;
      }
    }

    // 7) rotate x prefetch
    bx0 = bxN0; bx1 = bxN1;
  }
}

extern "C" void kernel_launch(void* const* d_in, const int* in_sizes, int n_in,
                              void* d_out, int out_size, void* d_ws, size_t ws_size,
                              hipStream_t stream) {
  const float* x_node = (const float*)d_in[0];
  const float* x_edge = (const float*)d_in[1];
  const int*   eidx   = (const int*)  d_in[2];
  const float* W_edge = (const float*)d_in[3];
  const float* b_edge = (const float*)d_in[4];
  const float* W_node = (const float*)d_in[5];
  const float* b_node = (const float*)d_in[6];
  const float* gamma  = (const float*)d_in[7];
  const float* beta   = (const float*)d_in[8];
  float* out = (float*)d_out;

  const int n_nodes = in_sizes[0] / 128;
  const int n_edges = in_sizes[2] / 2;

  short* h_node = (short*)d_ws;
  if (ws_size < (size_t)n_nodes * 128 * sizeof(short)) return;  // ws too small

  node_mfma_kernel<<<512, 256, 0, stream>>>(x_node, W_node, b_node, h_node, n_nodes);
  edge_mfma_kernel<<<2048, 256, 0, stream>>>(x_edge, eidx, W_edge, b_edge,
                                             h_node, gamma, beta, out, n_edges);
}